// Round 7
// baseline (121.346 us; speedup 1.0000x reference)
//
#include <hip/hip_runtime.h>

#define B_   8
#define N_   512
#define IND  256
#define H_   4
#define PH   32
#define OD   128   // H_*PH
#define TI   4     // targets per block (attn)

typedef float v2f __attribute__((ext_vector_type(2)));

// leaky 0.4 * log2(e), and 0.6 * log2(e): logits in log2 domain -> v_exp_f32.
#define ATT_SCALE 0.5770780163555854f
#define DLR_SCALE 0.8656170245333781f

template <int PAT>
__device__ __forceinline__ float dpp_add(float x) {
    int yi = __builtin_amdgcn_mov_dpp(__float_as_int(x), PAT, 0xF, 0xF, true);
    return x + __int_as_float(yi);
}

__device__ __forceinline__ float fast_exp2(float x) {
#if __has_builtin(__builtin_amdgcn_exp2f)
    return __builtin_amdgcn_exp2f(x);
#else
    return exp2f(x);
#endif
}

// Packed fp32 FMA: d += a*b on both halves, ONE VOP3P instruction.
__device__ __forceinline__ void pk_fma(v2f& d, v2f a, v2f b) {
    asm("v_pk_fma_f32 %0, %1, %2, %0" : "+v"(d) : "v"(a), "v"(b));
}

// Packed fp32 add: one VOP3P instruction for two adds (no abs modifier on
// VOP3P, so the |.| consumer stays scalar -- but the ADD itself packs 2:1).
__device__ __forceinline__ v2f pk_add(v2f a, v2f b) {
    v2f d;
    asm("v_pk_add_f32 %0, %1, %2" : "=v"(d) : "v"(a), "v"(b));
    return d;
}

// ---------------------------------------------------------------------------
// Kernel 1 v8: xl = x@Wl + bl ; xr = x@Wr + br  plus pre-scaled rank-1 parts.
// r6 post-mortem: proj ~36us vs 3.4us issue floor with W traffic already
// minimal (256KB/block, read once) -> latency-bound at 4 waves/SIMD. v8
// applies the fix that worked for attn: in-block K-split doubled.
//   512 thr = og(32) x ks(8 K-slices of 32) x which(2); 4 rows/block;
//   grid 1024 -> 4 blocks/CU x 8 waves = 32 waves/CU = 8 waves/SIMD.
// W read EXACTLY once per block (unchanged); 1-deep parity W prefetch;
// per-wave inter-chunk gap ~500cyc -> L2 latency covered by TLP.
// LDS: xs 4KB + comb[8][64][17] 34.8KB = 38.8KB -> 4 blocks/CU fits.
// VGPR ~52 < 64 cap from __launch_bounds__(512,4).
// ---------------------------------------------------------------------------
__global__ __launch_bounds__(512, 4) void proj_kernel(
    const float* __restrict__ x,
    const float* __restrict__ Wl, const float* __restrict__ bl,
    const float* __restrict__ Wr, const float* __restrict__ br,
    const float* __restrict__ att,
    float* __restrict__ xl, float* __restrict__ xr,
    float* __restrict__ dl, float* __restrict__ dr)
{
    __shared__ float xs[4 * IND];        // 4 KB
    __shared__ float comb[8][64][17];    // 34816 B

    const int t = threadIdx.x;
    const int row0 = blockIdx.x * 4;

    if (t < 256)
        ((float4*)xs)[t] = ((const float4*)(x + (size_t)row0 * IND))[t];
    __syncthreads();

    const int og    = t & 31;        // col quad: cols og*4 .. og*4+3
    const int ks    = (t >> 5) & 7;  // K slice: k0 = ks*32
    const int which = t >> 8;        // 0: Wl->xl/dl, 1: Wr->xr/dr
    const int o0 = og * 4;
    const int k0 = ks * 32;
    const float* W = (which ? Wr : Wl) + (size_t)k0 * OD + o0;

    float acc[4][4];
    #pragma unroll
    for (int r = 0; r < 4; ++r)
        #pragma unroll
        for (int c = 0; c < 4; ++c) acc[r][c] = 0.f;

    float4 wb[2][2];
    wb[0][0] = *(const float4*)(W);
    wb[0][1] = *(const float4*)(W + OD);

    #pragma unroll 2
    for (int s = 0; s < 16; ++s) {       // 16 chunks of 2 k (K=32 per thread)
        const int cur = s & 1, nxt = cur ^ 1;
        if (s < 15) {
            const float* Wq = W + (size_t)(2 * (s + 1)) * OD;
            wb[nxt][0] = *(const float4*)(Wq);
            wb[nxt][1] = *(const float4*)(Wq + OD);
        }
        #pragma unroll
        for (int r = 0; r < 4; ++r) {
            float2 xv = *(const float2*)(&xs[r * IND + k0 + 2 * s]);
            acc[r][0] = fmaf(xv.x, wb[cur][0].x, acc[r][0]);
            acc[r][1] = fmaf(xv.x, wb[cur][0].y, acc[r][1]);
            acc[r][2] = fmaf(xv.x, wb[cur][0].z, acc[r][2]);
            acc[r][3] = fmaf(xv.x, wb[cur][0].w, acc[r][3]);
            acc[r][0] = fmaf(xv.y, wb[cur][1].x, acc[r][0]);
            acc[r][1] = fmaf(xv.y, wb[cur][1].y, acc[r][1]);
            acc[r][2] = fmaf(xv.y, wb[cur][1].z, acc[r][2]);
            acc[r][3] = fmaf(xv.y, wb[cur][1].w, acc[r][3]);
        }
    }

    // stage ALL 8 K-slice partials (banks (17*pid+i)%32: pid-bijective, 2-way)
    const int pid = og | (which << 5);   // 0..63
    #pragma unroll
    for (int i = 0; i < 16; ++i)
        comb[ks][pid][i] = acc[i >> 2][i & 3];
    __syncthreads();

    // final: 512 threads -> (which', row', col-pair); one float2 output each
    const int cf  = t & 63;          // col pair: cols cf*2, cf*2+1
    const int rf  = (t >> 6) & 3;
    const int whf = t >> 8;
    const int pidf = (cf >> 1) | (whf << 5);
    const int ci   = (cf & 1) * 2;
    const float* bb = whf ? br : bl;
    float* dst = whf ? xr : xl;
    float* dp  = whf ? dr : dl;
    float2 bv = *(const float2*)(bb + cf * 2);
    float2 av = *(const float2*)(att + cf * 2);
    float y[2];
    #pragma unroll
    for (int c = 0; c < 2; ++c) {
        const int idx = rf * 4 + ci + c;
        float s01 = comb[0][pidf][idx] + comb[1][pidf][idx];
        float s23 = comb[2][pidf][idx] + comb[3][pidf][idx];
        float s45 = comb[4][pidf][idx] + comb[5][pidf][idx];
        float s67 = comb[6][pidf][idx] + comb[7][pidf][idx];
        y[c] = ((s01 + s23) + (s45 + s67)) + ((c == 0) ? bv.x : bv.y);
    }
    *(float2*)(&dst[(size_t)(row0 + rf) * OD + cf * 2]) =
        make_float2(y[0], y[1]);
    // rank-1 part: dl/dr[n,h] = 0.6*log2e * sum_c att[h,c]*y[c]
    // reduce over the 16 col-pair lanes of one head (head = cf>>4)
    float dc = fmaf(av.x, y[0], av.y * y[1]);
    dc += __shfl_xor(dc, 1);
    dc += __shfl_xor(dc, 2);
    dc += __shfl_xor(dc, 4);
    dc += __shfl_xor(dc, 8);
    if ((cf & 15) == 0)
        dp[(size_t)(row0 + rf) * H_ + (cf >> 4)] = DLR_SCALE * dc;
}

// ---------------------------------------------------------------------------
// Kernel 2 v8: masked-softmax attention aggregate. v7 structure UNCHANGED
// (40.9us, no spill, drv-cancellation proven) except the e2 adds now use
// v_pk_add_f32: s-pairs computed 2-per-instr, |s| fma stays scalar (VOP3P
// has no abs modifier). 16 -> 12 instr per (il,u) e2 block, ~-14% main-loop
// VALU. No new register state: v2f aliases the same VGPR pairs.
// 512-thr blocks, js=32 j-slices, u=16; 4 blocks/CU x 8 waves = 32 waves/CU.
// XCD<->batch swizzle kept; 2-pass conflict-free LDS epilogue kept.
// ---------------------------------------------------------------------------
__global__ __launch_bounds__(512, 4) void attn_kernel(
    const int* __restrict__ adj, const float* __restrict__ att,
    const float* __restrict__ bias,
    const float* __restrict__ xl, const float* __restrict__ xr,
    const float* __restrict__ dl, const float* __restrict__ dr,
    float* __restrict__ out)
{
    __shared__ float sacc[H_][2][32][PH + 1];  // 33792 B (two il per pass)
    __shared__ float ssum[H_][32][TI];         // 2 KB

    const int t = threadIdx.x;
    const int bid = (blockIdx.x & 7) * 128 + (blockIdx.x >> 3);
    const int b  = bid >> 7;
    const int i0 = (bid & 127) * TI;
    const int cq = t & 3;
    const int js = (t >> 2) & 31;   // 32 j-slices
    const int h  = t >> 7;
    const int cbase = h * PH + cq * 8;

    // preload att (pre-scaled by 0.4*log2e) and xr pair-fragments (v2f)
    float atS[8];
    {
        const float* ap = att + cbase;
        float4 a0 = *(const float4*)(ap);
        float4 a1 = *(const float4*)(ap + 4);
        atS[0] = ATT_SCALE * a0.x; atS[1] = ATT_SCALE * a0.y;
        atS[2] = ATT_SCALE * a0.z; atS[3] = ATT_SCALE * a0.w;
        atS[4] = ATT_SCALE * a1.x; atS[5] = ATT_SCALE * a1.y;
        atS[6] = ATT_SCALE * a1.z; atS[7] = ATT_SCALE * a1.w;
    }
    v2f xrv[TI][4];
    #pragma unroll
    for (int il = 0; il < TI; ++il) {
        const float* xp = xr + ((size_t)(b * N_ + i0 + il)) * OD + cbase;
        float4 r0 = *(const float4*)(xp);
        float4 r1 = *(const float4*)(xp + 4);
        xrv[il][0] = (v2f){r0.x, r0.y};
        xrv[il][1] = (v2f){r0.z, r0.w};
        xrv[il][2] = (v2f){r1.x, r1.y};
        xrv[il][3] = (v2f){r1.z, r1.w};
    }

    v2f acc[TI][4];
    float sumw[TI];
    #pragma unroll
    for (int il = 0; il < TI; ++il) {
        sumw[il] = 0.f;
        #pragma unroll
        for (int m = 0; m < 4; ++m) acc[il][m] = (v2f){0.f, 0.f};
    }

    // software-pipelined j-loop: j = u*32 + js, u = 0..15
    const float* xlp = xl + ((size_t)(b * N_ + js)) * OD + cbase;
    const int*   ajp = adj + ((size_t)(b * N_ + js)) * N_ + i0;
    const float* dlp = dl + ((size_t)(b * N_ + js)) * H_ + h;

    float4 va = *(const float4*)(xlp);
    float4 vb = *(const float4*)(xlp + 4);
    int4   mj = *(const int4*)(ajp);
    float  dj = *dlp;

    #pragma unroll 2
    for (int u = 0; u < 16; ++u) {
        float4 wa = va, wb = vb;
        int4   wm = mj;
        float  wd = dj;
        if (u < 15) {
            xlp += 32 * OD; ajp += 32 * N_; dlp += 32 * H_;
            va = *(const float4*)(xlp);
            vb = *(const float4*)(xlp + 4);
            mj = *(const int4*)(ajp);
            dj = *dlp;
        }
        const int j = u * 32 + js;
        v2f p0 = (v2f){wa.x, wa.y}, p1 = (v2f){wa.z, wa.w};
        v2f p2 = (v2f){wb.x, wb.y}, p3 = (v2f){wb.z, wb.w};
        int wmv[TI] = {wm.x, wm.y, wm.z, wm.w};
        #pragma unroll
        for (int il = 0; il < TI; ++il) {
            v2f s01 = pk_add(xrv[il][0], p0);
            v2f s23 = pk_add(xrv[il][1], p1);
            v2f s45 = pk_add(xrv[il][2], p2);
            v2f s67 = pk_add(xrv[il][3], p3);
            float e2a = 0.f, e2b = 0.f;
            e2a = fmaf(atS[0], __builtin_fabsf(s01.x), e2a);
            e2b = fmaf(atS[1], __builtin_fabsf(s01.y), e2b);
            e2a = fmaf(atS[2], __builtin_fabsf(s23.x), e2a);
            e2b = fmaf(atS[3], __builtin_fabsf(s23.y), e2b);
            e2a = fmaf(atS[4], __builtin_fabsf(s45.x), e2a);
            e2b = fmaf(atS[5], __builtin_fabsf(s45.y), e2b);
            e2a = fmaf(atS[6], __builtin_fabsf(s67.x), e2a);
            e2b = fmaf(atS[7], __builtin_fabsf(s67.y), e2b);
            float eh = e2a + e2b;
            eh = dpp_add<0xB1>(eh);          // + lane^1 (quad_perm 1,0,3,2)
            eh = dpp_add<0x4E>(eh);          // + lane^2 (quad_perm 2,3,0,1)
            float e = wd + eh;               // log2 logit (drv cancels in softmax)
            bool keep = (wmv[il] != 0) || (j == i0 + il);
            float w = keep ? fast_exp2(e) : 0.f;
            sumw[il] += w;
            v2f ws = (v2f){w, w};
            pk_fma(acc[il][0], ws, p0);
            pk_fma(acc[il][1], ws, p1);
            pk_fma(acc[il][2], ws, p2);
            pk_fma(acc[il][3], ws, p3);
        }
    }

    // ---- epilogue: two il-passes through LDS; reduce over the 32 js ----
    if (cq == 0) {
        #pragma unroll
        for (int il = 0; il < TI; ++il)
            ssum[h][js][il] = sumw[il];
    }
    // pass 0: il 0,1   (write banks (js+8cq)%32: exactly 2-way, free)
    #pragma unroll
    for (int p = 0; p < 2; ++p) {
        *(float4*)(&sacc[h][p][js][cq * 8]) =
            make_float4(acc[p][0].x, acc[p][0].y, acc[p][1].x, acc[p][1].y);
        *(float4*)(&sacc[h][p][js][cq * 8 + 4]) =
            make_float4(acc[p][2].x, acc[p][2].y, acc[p][3].x, acc[p][3].y);
    }
    __syncthreads();
    if (t < 256) {
        const int c   = t & 31;
        const int ilr = (t >> 5) & 1;
        const int hr  = t >> 6;
        float a = 0.f, st = 0.f;
        #pragma unroll
        for (int k = 0; k < 32; ++k) {
            a  += sacc[hr][ilr][k][c];       // banks (k+c)%32: conflict-free
            st += ssum[hr][k][ilr];
        }
        const int cg = hr * PH + c;
        out[((size_t)(b * N_ + i0 + ilr)) * OD + cg] =
            fmaf(a, 1.f / st, bias[cg]);
    }
    __syncthreads();
    // pass 1: il 2,3
    #pragma unroll
    for (int p = 0; p < 2; ++p) {
        *(float4*)(&sacc[h][p][js][cq * 8]) =
            make_float4(acc[2 + p][0].x, acc[2 + p][0].y,
                        acc[2 + p][1].x, acc[2 + p][1].y);
        *(float4*)(&sacc[h][p][js][cq * 8 + 4]) =
            make_float4(acc[2 + p][2].x, acc[2 + p][2].y,
                        acc[2 + p][3].x, acc[2 + p][3].y);
    }
    __syncthreads();
    if (t < 256) {
        const int c   = t & 31;
        const int ilr = (t >> 5) & 1;
        const int hr  = t >> 6;
        float a = 0.f, st = 0.f;
        #pragma unroll
        for (int k = 0; k < 32; ++k) {
            a  += sacc[hr][ilr][k][c];
            st += ssum[hr][k][2 + ilr];
        }
        const int cg = hr * PH + c;
        out[((size_t)(b * N_ + i0 + 2 + ilr)) * OD + cg] =
            fmaf(a, 1.f / st, bias[cg]);
    }
}

extern "C" void kernel_launch(void* const* d_in, const int* in_sizes, int n_in,
                              void* d_out, int out_size, void* d_ws, size_t ws_size,
                              hipStream_t stream) {
    const float* x    = (const float*)d_in[0];
    const int*   adj  = (const int*)d_in[1];
    const float* Wl   = (const float*)d_in[2];
    const float* bl   = (const float*)d_in[3];
    const float* Wr   = (const float*)d_in[4];
    const float* br   = (const float*)d_in[5];
    const float* att  = (const float*)d_in[6];
    const float* bias = (const float*)d_in[7];
    float* out = (float*)d_out;

    float* xl = (float*)d_ws;                    // 2 MB
    float* xr = xl + (size_t)B_ * N_ * OD;       // 2 MB
    float* dl = xr + (size_t)B_ * N_ * OD;       // 64 KB
    float* dr = dl + (size_t)B_ * N_ * H_;       // 64 KB

    proj_kernel<<<1024, 512, 0, stream>>>(x, Wl, bl, Wr, br, att, xl, xr, dl, dr);
    attn_kernel<<<1024, 512, 0, stream>>>(adj, att, bias, xl, xr, dl, dr, out);
}